// Round 4
// baseline (448.925 us; speedup 1.0000x reference)
//
#include <hip/hip_runtime.h>

// ---------------------------------------------------------------------------
// MambaLayer on MI355X (gfx950).
// Pipeline (all f16 MFMA with fp32 accumulate; scan/elementwise in fp32):
//   1. convert x -> f16; transpose-convert W_in, W_out -> N-major f16 (B^T form)
//   2. GEMM1: xr = x @ W_in          (16384x4096x1024)
//   3. conv_bc_fin: conv(3)+SiLU -> xc  AND  BtCt = xc @ [W_B|W_C] (MFMA)
//   4. scan_p2: carry propagation across chunks (tiny)
//   5. scan_p3_fuse: replay chunk scan -> ys, y-fuse -> overwrite xc (f16)
//   6. GEMM2: out = y @ W_out        (16384x1024x2048), fp32 out
//
// R6: gemm256 8-phase 256^2 BK=64 counted-vmcnt. 450us; GEMM1 157.7us.
// R7/R8: B-dedup half-pipeline. 437us; GEMM1 148.5us (926 TF, MfmaUtil 39%).
//     Post-mortem: 5571 cyc/tile vs floors {LDS-read 2313, MFMA 621} ->
//     still near-serialized: (mq,nq) phases consume same-phase reads, all
//     waves barrier-locked -> CU drains LDS with MFMA idle and vice versa.
// R9: wave re-tile 2Mx4N -> 4Mx2N (64x128/wave): af (8 reads) loaded ONCE
//     per tile, reused all 4 phases; phases = 4 col-blocks of 32, B-operand
//     (4 reads) double-buffered bfA/bfB and always read ONE PHASE EARLY.
//     af(t)+bfA(cb0,t) read at p3(t-1) after gate+barrier. Steady-state
//     lgkm wait = lgkmcnt(4) every phase, never 0: all reads drain under
//     MFMA. Stage ring {p0: Ah1+Bh0(t+1); p1: Bh1(t+1); p2: Ah0(t+2)},
//     gate vmcnt(2) at p3. Slot WAR re-proved: every rewrite >=1 barrier
//     after victim-read retirement (lgkm-before-MFMA precedes a barrier
//     all waves pass). Same 192 frag VGPRs as R7 (fits 256 cap).
// ---------------------------------------------------------------------------

typedef _Float16 half8 __attribute__((ext_vector_type(8)));
typedef float floatx4 __attribute__((ext_vector_type(4)));

#define D_MODEL 1024
#define D_INNER 2048
#define SEQ     4096
#define NBATCH  4
#define NROWS   (NBATCH * SEQ)        // 16384
#define CHUNK   16
#define NCHUNK  (SEQ / CHUNK)         // 256 chunks per batch
#define NTASK   (NBATCH * NCHUNK)     // 1024 chunk-tasks

__device__ __forceinline__ void async16(_Float16* lds, const _Float16* g) {
    // global -> LDS direct copy, 16B per lane; LDS dest = wave-uniform base + lane*16
    __builtin_amdgcn_global_load_lds((const __attribute__((address_space(1))) void*)g,
                                     (__attribute__((address_space(3))) void*)lds, 16, 0, 0);
}

__device__ __forceinline__ float siluf(float x) {
    return x / (1.f + __expf(-x));
}

__device__ __forceinline__ float decay_of(const float* A, int s) {
    return __expf(-log1pf(__expf(A[s])));   // exp(-softplus(A[s]))
}

// --------------------------- conversion kernels ----------------------------

__global__ __launch_bounds__(256) void convert_f32_f16(const float* __restrict__ src,
                                                       _Float16* __restrict__ dst) {
    size_t idx = ((size_t)blockIdx.x * 256 + threadIdx.x) * 8;
    float4 a = *(const float4*)(src + idx);
    float4 b = *(const float4*)(src + idx + 4);
    half8 o = {(_Float16)a.x, (_Float16)a.y, (_Float16)a.z, (_Float16)a.w,
               (_Float16)b.x, (_Float16)b.y, (_Float16)b.z, (_Float16)b.w};
    *(half8*)(dst + idx) = o;
}

// src: K x N fp32 (row-major), dst: N x K f16 (row-major)  [i.e. B^T]
__global__ __launch_bounds__(256) void transpose_to_f16(const float* __restrict__ src,
                                                        _Float16* __restrict__ dst,
                                                        int K, int N) {
    __shared__ float tile[32][33];
    int n0 = blockIdx.x * 32, k0 = blockIdx.y * 32;
    int x = threadIdx.x, y = threadIdx.y;   // 32 x 8
#pragma unroll
    for (int r = 0; r < 32; r += 8)
        tile[y + r][x] = src[(size_t)(k0 + y + r) * N + (n0 + x)];
    __syncthreads();
#pragma unroll
    for (int r = 0; r < 32; r += 8)
        dst[(size_t)(n0 + y + r) * K + (k0 + x)] = (_Float16)tile[x][y + r];
}

// WBCT[n][k], n<16 -> W_B[:,n], n>=16 -> W_C[:,n-16]; shape 32 x 2048 f16
__global__ __launch_bounds__(256) void convert_wbct(const float* __restrict__ WB,
                                                    const float* __restrict__ WC,
                                                    _Float16* __restrict__ WBCT) {
    int idx = blockIdx.x * 256 + threadIdx.x;   // 0 .. 65535
    int n = idx >> 11, k = idx & 2047;
    float v = (n < 16) ? WB[k * 16 + n] : WC[k * 16 + (n - 16)];
    WBCT[idx] = (_Float16)v;
}

// ------------------------------- main GEMM ---------------------------------
// C(MxN) = A(MxK) * B(KxN), B given as BT (NxK row-major). f16 in, fp32 acc.
// 256x256 tile, BK=64, 512 threads = 8 waves as 4M x 2N (wm 0..3 = 64-row
// slab, wn 0..1 = 128-col half); per-wave output 64x128 = 4x8 frags of
// 16x16. LDS 128 KiB: A/B double-buffered per K-tile, each 256x64 f16 in
// 2 halves of 128 rows. 16B-chunk XOR swizzle: chunk c of row r at c^(r&7)
// (staging permutes the GLOBAL source column; LDS dest stays linear).
//
// Per K-tile t, phases p0..p3 = col-blocks cb0..cb3 (32 cols each):
//   af (A frags, 8 reads) loaded ONCE at p3(t-1) after gate+barrier,
//   reused all 4 phases. B-operand for phase p read at phase p-1 into
//   alternating bfA/bfB (4 reads). Steady-state MFMA waits lgkmcnt(4).
//   Stage ring: p0: Ah1(t+1)+Bh0(t+1); p1: Bh1(t+1); p2: Ah0(t+2);
//   p3: gate vmcnt(2) [tile t+1 landed; Ah0(t+2)'s 2 loads in flight],
//   barrier, read bfA(cb0,t+1)+af(t+1) around the MFMA.
// Slot WAR safety: every restage targets a slot whose last ds_read retired
// (lgkm wait precedes that phase's MFMA, which precedes a barrier ALL
// waves passed) >=1 barrier before the stage issue.

__device__ __forceinline__ void stage_half(const _Float16* __restrict__ src, int K,
                                           int rowBase, int k0, _Float16* ldsHalf) {
    const int tid = threadIdx.x;
    const int sr = tid >> 3, wid = tid >> 6;
    const int lc = ((tid & 7) ^ (sr & 7)) << 3;     // swizzled source col (elements)
#pragma unroll
    for (int r = 0; r < 2; r++) {
        const _Float16* g = src + (size_t)(rowBase + r * 64 + sr) * K + (k0 + lc);
        async16(ldsHalf + r * 4096 + wid * 512, g);
    }
}

__device__ __forceinline__ void loadA8(half8 af[4][2], const _Float16* p,
                                       int sw0, int sw1) {
#pragma unroll
    for (int m = 0; m < 4; m++) {
        af[m][0] = *(const half8*)(p + m * 1024 + sw0);
        af[m][1] = *(const half8*)(p + m * 1024 + sw1);
    }
}

__device__ __forceinline__ void loadB4(half8 bf[2][2], const _Float16* p,
                                       int sw0, int sw1) {
#pragma unroll
    for (int n = 0; n < 2; n++) {
        bf[n][0] = *(const half8*)(p + n * 1024 + sw0);
        bf[n][1] = *(const half8*)(p + n * 1024 + sw1);
    }
}

#define GP_MMA(CB, BF)                                                                  \
    __builtin_amdgcn_s_barrier();                                                       \
    __builtin_amdgcn_s_setprio(1);                                                      \
    _Pragma("unroll") for (int m = 0; m < 4; m++)                                       \
        _Pragma("unroll") for (int n = 0; n < 2; n++)                                   \
            _Pragma("unroll") for (int s = 0; s < 2; s++)                               \
                acc[m][(CB) * 2 + n] = __builtin_amdgcn_mfma_f32_16x16x32_f16(          \
                    af[m][s], (BF)[n][s], acc[m][(CB) * 2 + n], 0, 0, 0);               \
    __builtin_amdgcn_s_setprio(0);                                                      \
    __builtin_amdgcn_s_barrier();

template <typename OutT>
__global__ __launch_bounds__(512, 2) void gemm256(const _Float16* __restrict__ A,
                                                  const _Float16* __restrict__ BT,
                                                  OutT* __restrict__ C,
                                                  int M, int N, int K) {
    __shared__ __align__(16) _Float16 smem[4 * 16384];   // 128 KiB: A0,A1,B0,B1
    _Float16* const AsBase = smem;
    _Float16* const BsBase = smem + 32768;

    const int tid = threadIdx.x;
    const int wid = tid >> 6, lane = tid & 63;
    const int wm = wid >> 1, wn = wid & 1;               // 4M x 2N waves
    const int fr = lane & 15, q = lane >> 4, frq = fr & 7;
    const int sw0 = (q ^ frq) << 3;                      // kk=0 swizzled chunk offset
    const int sw1 = ((4 + q) ^ frq) << 3;                // kk=1
    const int aB0 = (wm * 64 + fr) * 64;                 // af row base (+m*1024)
    const int bB0 = (wn * 128 + fr) * 64;                // bf base (+cb*2048 +n*1024)

    // XCD-chunked bijective swizzle: dispatch slot lin runs on XCD lin%8;
    // give each XCD a contiguous range of logical ids -> 8 full A-row-panels.
    int lin = blockIdx.y * gridDim.x + blockIdx.x;
    const int nwg = gridDim.x * gridDim.y;               // multiple of 8 here
    lin = (lin & 7) * (nwg >> 3) + (lin >> 3);
    const int bx = lin % gridDim.x, by = lin / gridDim.x;
    const int row0 = by * 256, col0 = bx * 256;
    const int NT = K >> 6;

    floatx4 acc[4][8] = {};
    half8 af[4][2], bfA[2][2], bfB[2][2];

    // Prologue: tile0 fully + tile1 A-h0 (mimics steady-state p2(t-1) stage).
    stage_half(A,  K, row0,       0, AsBase);            // t0 A-h0
    stage_half(A,  K, row0 + 128, 0, AsBase + 8192);     // t0 A-h1
    stage_half(BT, K, col0,       0, BsBase);            // t0 B-h0
    stage_half(BT, K, col0 + 128, 0, BsBase + 8192);     // t0 B-h1
    if (NT > 1) {
        stage_half(A, K, row0, 64, AsBase + 16384);      // t1 A-h0
        asm volatile("s_waitcnt vmcnt(2)" ::: "memory");
    } else {
        asm volatile("s_waitcnt vmcnt(0)" ::: "memory");
    }
    __builtin_amdgcn_s_barrier();
    asm volatile("" ::: "memory");                       // no LDS-read hoist above barrier
    loadB4(bfA, BsBase + bB0, sw0, sw1);                 // t0 cb0
    loadA8(af, AsBase + aB0, sw0, sw1);                  // t0 A frags (all phases)

    for (int t = 0; t < NT; ++t) {
        _Float16* Ab  = AsBase + ((t & 1) << 14);
        _Float16* Bb  = BsBase + ((t & 1) << 14);
        _Float16* Abn = AsBase + (((t + 1) & 1) << 14);
        _Float16* Bbn = BsBase + (((t + 1) & 1) << 14);
        const int k1 = (t + 1) << 6, k2 = (t + 2) << 6;
        const bool s1 = (t + 1) < NT, s2 = (t + 2) < NT;

        // p0: MFMA(cb0, bfA); read bfB<-cb1; stage Ah1(t+1), Bh0(t+1)
        loadB4(bfB, Bb + bB0 + 2048, sw0, sw1);
        if (s1) {
            stage_half(A,  K, row0 + 128, k1, Abn + 8192);
            stage_half(BT, K, col0,       k1, Bbn);
        }
        GP_MMA(0, bfA);

        // p1: MFMA(cb1, bfB); read bfA<-cb2; stage Bh1(t+1)
        loadB4(bfA, Bb + bB0 + 4096, sw0, sw1);
        if (s1) stage_half(BT, K, col0 + 128, k1, Bbn + 8192);
        GP_MMA(1, bfB);

        // p2: MFMA(cb2, bfA); read bfB<-cb3; stage Ah0(t+2)
        loadB4(bfB, Bb + bB0 + 6144, sw0, sw1);
        if (s2) stage_half(A, K, row0, k2, Ab);
        GP_MMA(2, bfA);

        // p3: gate; barrier(open); read bfA<-cb0(t+1); MFMA(cb3, bfB);
        //     read af(t+1); barrier(close)
        if (s2) {
            asm volatile("s_waitcnt vmcnt(2)" ::: "memory");
        } else if (s1) {
            asm volatile("s_waitcnt vmcnt(0)" ::: "memory");
        }
        __builtin_amdgcn_s_barrier();
        asm volatile("" ::: "memory");                   // no hoist above gate+barrier
        if (s1) loadB4(bfA, Bbn + bB0, sw0, sw1);
        __builtin_amdgcn_s_setprio(1);
#pragma unroll
        for (int m = 0; m < 4; m++)
#pragma unroll
            for (int n = 0; n < 2; n++)
#pragma unroll
                for (int s = 0; s < 2; s++)
                    acc[m][6 + n] = __builtin_amdgcn_mfma_f32_16x16x32_f16(
                        af[m][s], bfB[n][s], acc[m][6 + n], 0, 0, 0);
        __builtin_amdgcn_s_setprio(0);
        if (s1) loadA8(af, Abn + aB0, sw0, sw1);         // next tile A frags
        __builtin_amdgcn_s_barrier();
    }

    // C/D layout: col = lane&15, row = (lane>>4)*4 + reg   [measured m89/m91]
    const int er = (lane >> 4) * 4, ec = lane & 15;
#pragma unroll
    for (int mi = 0; mi < 4; mi++)
#pragma unroll
        for (int cj = 0; cj < 8; cj++)
#pragma unroll
            for (int r = 0; r < 4; r++) {
                int row = row0 + wm * 64 + mi * 16 + er + r;
                int col = col0 + wn * 128 + cj * 16 + ec;
                C[(size_t)row * N + col] = (OutT)acc[mi][cj][r];
            }
}

// ---------------- fused conv + silu + Bt/Ct (MFMA) + scan p1 ----------------
// Block = 32 rows (2 chunks), 256 threads = 4 waves. Waves own disjoint K
// quarters (512 cols = 4 panels of 128) -> NO barriers in the main loop.
__global__ __launch_bounds__(256) void conv_bc_fin(const _Float16* __restrict__ xr,
                                                   const float* __restrict__ cw,
                                                   const float* __restrict__ cb,
                                                   const _Float16* __restrict__ WBCT,
                                                   const float* __restrict__ A,
                                                   _Float16* __restrict__ xc,
                                                   float* __restrict__ BtCt,
                                                   float* __restrict__ fin) {
    __shared__ __align__(16) _Float16 As[4 * 32 * 128];   // 32 KB; reused in epilogue
    const int tid = threadIdx.x, wid = tid >> 6, lane = tid & 63;
    const int row0 = blockIdx.x * 32;
    const int l0 = row0 & (SEQ - 1);
    const int cg = lane & 15;            // col-group within panel (8 cols)
    const int rg = lane >> 4;            // row-group (8 rows)
    const int fr = lane & 15, q = lane >> 4;
    _Float16* As_w = As + wid * 4096;
    const int r0 = rg * 8;

    floatx4 acc[2][2] = {};

    for (int t = 0; t < 4; t++) {
        const int kbase = wid * 512 + t * 128;
        const int gcol = kbase + cg * 8;
        float w0[8], w1[8], w2[8], bb[8];
#pragma unroll
        for (int j = 0; j < 8; j++) {
            w0[j] = cw[(gcol + j) * 3];
            w1[j] = cw[(gcol + j) * 3 + 1];
            w2[j] = cw[(gcol + j) * 3 + 2];
            bb[j] = cb[gcol + j];
        }
        half8 prev = {}, cur, nxt;
        if (!(l0 == 0 && rg == 0))
            prev = *(const half8*)(xr + (size_t)(row0 + r0 - 1) * 4096 + gcol);
        cur = *(const half8*)(xr + (size_t)(row0 + r0) * 4096 + gcol);
#pragma unroll
        for (int r = 0; r < 8; r++) {
            if (r == 7 && rg == 3 && l0 + 32 == SEQ) {
                half8 z = {};
                nxt = z;
            } else {
                nxt = *(const half8*)(xr + (size_t)(row0 + r0 + r + 1) * 4096 + gcol);
            }
            half8 o;
#pragma unroll
            for (int j = 0; j < 8; j++) {
                float a = (float)prev[j] * w0[j] + (float)cur[j] * w1[j] +
                          (float)nxt[j] * w2[j] + bb[j];
                o[j] = (_Float16)siluf(a);
            }
            const int lrow = r0 + r;
            *(half8*)(xc + (size_t)(row0 + lrow) * D_INNER + gcol) = o;
            *(half8*)(As_w + lrow * 128 + ((cg ^ (lrow & 7)) * 8)) = o;
            prev = cur;
            cur = nxt;
        }
#pragma unroll
        for (int ks = 0; ks < 4; ks++) {
            half8 af[2], bf[2];
#pragma unroll
            for (int rt = 0; rt < 2; rt++)
                af[rt] = *(const half8*)(As_w + (rt * 16 + fr) * 128 +
                                         (((ks * 4 + q) ^ (fr & 7)) * 8));
#pragma unroll
            for (int ot = 0; ot < 2; ot++)
                bf[ot] = *(const half8*)(WBCT + (size_t)(ot * 16 + fr) * D_INNER +
                                         kbase + ks * 32 + q * 8);
#pragma unroll
            for (int rt = 0; rt < 2; rt++)
#pragma unroll
                for (int ot = 0; ot < 2; ot++)
                    acc[rt][ot] = __builtin_amdgcn_mfma_f32_16x16x32_f16(af[rt], bf[ot], acc[rt][ot], 0, 0, 0);
        }
    }

    __syncthreads();                       // all waves done reading As as f16
    float* red = (float*)As;               // [wid][row 32][out 32] = 4096 f32 (16 KB)
    float* btl = (float*)As + 4096;        // [row 32][out 32] = 1024 f32 (4 KB)
    const int er = (lane >> 4) * 4, ec = lane & 15;
#pragma unroll
    for (int rt = 0; rt < 2; rt++)
#pragma unroll
        for (int ot = 0; ot < 2; ot++)
#pragma unroll
            for (int rr = 0; rr < 4; rr++)
                red[wid * 1024 + (rt * 16 + er + rr) * 32 + ot * 16 + ec] = acc[rt][ot][rr];
    __syncthreads();
#pragma unroll
    for (int i = 0; i < 4; i++) {
        int idx = i * 256 + tid;           // (row<<5)|out
        float v = red[idx] + red[1024 + idx] + red[2048 + idx] + red[3072 + idx];
        btl[idx] = v;
        BtCt[(size_t)row0 * 32 + idx] = v; // (row0+row)*32+out == row0*32+idx
    }
    __syncthreads();
    if (tid < 32) {                        // 2 chunks x 16 states
        const int ch = tid >> 4, s = tid & 15;
        const float decay = decay_of(A, s);
        float st = 0.f;
#pragma unroll
        for (int r = 0; r < CHUNK; r++)
            st = st * decay + btl[(ch * 16 + r) * 32 + s];
        fin[((row0 >> 4) + ch) * 16 + s] = st;
    }
}

// -------------------------------- scan -------------------------------------
// phase 2: carry propagation across chunks. 1 block x 64 threads (b,s).
__global__ __launch_bounds__(64) void scan_p2(const float* __restrict__ fin,
                                              const float* __restrict__ A,
                                              float* __restrict__ carry) {
    int t = threadIdx.x;
    int b = t >> 4, s = t & 15;
    float decay = decay_of(A, s);
    float d16 = decay;
#pragma unroll
    for (int k = 0; k < 4; k++) d16 *= d16;     // decay^16
    float cy = 0.f;
#pragma unroll 8
    for (int c = 0; c < NCHUNK; c++) {
        int idx = ((b * NCHUNK) + c) * 16 + s;
        carry[idx] = cy;
        cy = cy * d16 + fin[idx];
    }
}

// phase 3 + y-fuse: replay chunk scan (lanes 0..15, Bt/Ct preloaded to regs)
// -> ys in LDS, then all 256 threads compute y = (ys + xc*D) * silu(res),
// overwriting xc (f16). 1024 blocks x 256 threads; block = chunk-task.
__global__ __launch_bounds__(256) void scan_p3_fuse(const float* __restrict__ BtCt,
                                                    const float* __restrict__ A,
                                                    const float* __restrict__ carry,
                                                    const float* __restrict__ D,
                                                    const _Float16* __restrict__ xr,
                                                    _Float16* __restrict__ xc) {
    __shared__ float ysl[CHUNK];
    const int task = blockIdx.x;
    const int b = task >> 8, c = task & (NCHUNK - 1);
    const int row0 = b * SEQ + c * CHUNK;
    const int tid = threadIdx.x;

    if (tid < 16) {
        const int s = tid;
        const float decay = decay_of(A, s);
        size_t r = (size_t)row0 * 32;
        float bt[CHUNK], ct[CHUNK];
#pragma unroll
        for (int j = 0; j < CHUNK; j++) {       // independent loads, ILP
            bt[j] = BtCt[r + (size_t)j * 32 + s];
            ct[j] = BtCt[r + (size_t)j * 32 + 16 + s];
        }
        float st = carry[task * 16 + s];
        float yv[CHUNK];
#pragma unroll
        for (int j = 0; j < CHUNK; j++) {       // serial FMA chain only
            st = st * decay + bt[j];
            yv[j] = st * ct[j];
        }
#pragma unroll
        for (int j = 0; j < CHUNK; j++) {       // 16 independent reduce chains
            float y = yv[j];
            y += __shfl_xor(y, 1, 16);
            y += __shfl_xor(y, 2, 16);
            y += __shfl_xor(y, 4, 16);
            y += __shfl_xor(y, 8, 16);
            if (s == 0) ysl[j] = y;
        }
    }
    __syncthreads();

#pragma unroll
    for (int it = 0; it < 16; it++) {
        int chunk = it * 256 + tid;            // 0..4095 (16 rows x 256 col-chunks)
        int rl = chunk >> 8;                   // row within chunk
        int colb = (chunk & 255) * 8;          // col offset (elements)
        size_t row = (size_t)(row0 + rl);
        float yv = ysl[rl];
        half8 x8 = *(const half8*)(xc + row * D_INNER + colb);
        half8 r8 = *(const half8*)(xr + row * 4096 + 2048 + colb);
        float4 d0 = *(const float4*)(D + colb);
        float4 d1 = *(const float4*)(D + colb + 4);
        half8 o;
        float dd[8] = {d0.x, d0.y, d0.z, d0.w, d1.x, d1.y, d1.z, d1.w};
#pragma unroll
        for (int j = 0; j < 8; j++) {
            float y = yv + (float)x8[j] * dd[j];
            o[j] = (_Float16)(y * siluf((float)r8[j]));
        }
        *(half8*)(xc + row * D_INNER + colb) = o;
    }
}

// ------------------------------- launcher ----------------------------------
extern "C" void kernel_launch(void* const* d_in, const int* in_sizes, int n_in,
                              void* d_out, int out_size, void* d_ws, size_t ws_size,
                              hipStream_t stream) {
    const float* x      = (const float*)d_in[0];
    const float* W_in   = (const float*)d_in[1];
    const float* conv_w = (const float*)d_in[2];
    const float* conv_b = (const float*)d_in[3];
    const float* W_B    = (const float*)d_in[4];
    const float* W_C    = (const float*)d_in[5];
    const float* A      = (const float*)d_in[6];
    const float* D      = (const float*)d_in[7];
    const float* W_out  = (const float*)d_in[8];
    float* out = (float*)d_out;

    char* ws = (char*)d_ws;
    size_t off = 0;
    auto alloc = [&](size_t bytes) { size_t o = off; off += (bytes + 255) & ~(size_t)255; return o; };
    _Float16* xh    = (_Float16*)(ws + alloc((size_t)NROWS * D_MODEL * 2));      // 33.5 MB
    _Float16* WinT  = (_Float16*)(ws + alloc((size_t)4096 * 1024 * 2));          //  8.4 MB
    _Float16* WoutT = (_Float16*)(ws + alloc((size_t)1024 * 2048 * 2));          //  4.2 MB
    _Float16* WBCT  = (_Float16*)(ws + alloc((size_t)32 * 2048 * 2));            //  0.13 MB
    _Float16* xr    = (_Float16*)(ws + alloc((size_t)NROWS * 4096 * 2));         //  134 MB
    _Float16* xc    = (_Float16*)(ws + alloc((size_t)NROWS * D_INNER * 2));      //   67 MB
    float*    BtCt  = (float*)(ws + alloc((size_t)NROWS * 32 * 4));              //    2 MB
    float*    fin   = (float*)(ws + alloc((size_t)NTASK * 16 * 4));              //  64 KB
    float*    carry = (float*)(ws + alloc((size_t)NTASK * 16 * 4));              //  64 KB

    // 1. conversions
    convert_f32_f16<<<(NROWS * D_MODEL) / (256 * 8), 256, 0, stream>>>(x, xh);
    transpose_to_f16<<<dim3(4096 / 32, 1024 / 32), dim3(32, 8), 0, stream>>>(W_in, WinT, 1024, 4096);
    transpose_to_f16<<<dim3(1024 / 32, 2048 / 32), dim3(32, 8), 0, stream>>>(W_out, WoutT, 2048, 1024);
    convert_wbct<<<(32 * 2048) / 256, 256, 0, stream>>>(W_B, W_C, WBCT);
    // 2. GEMM1: xr = x @ W_in   (16384x4096x1024)
    gemm256<_Float16><<<dim3(4096 / 256, NROWS / 256), 512, 0, stream>>>(xh, WinT, xr, NROWS, 4096, 1024);
    // 3. conv + silu + Bt/Ct + fin (fused, MFMA)
    conv_bc_fin<<<NROWS / 32, 256, 0, stream>>>(xr, conv_w, conv_b, WBCT, A, xc, BtCt, fin);
    // 4. scan phase 2
    scan_p2<<<1, 64, 0, stream>>>(fin, A, carry);
    // 5. scan phase 3 + y-fuse
    scan_p3_fuse<<<NTASK, 256, 0, stream>>>(BtCt, A, carry, D, xr, xc);
    // 6. GEMM2: out = y @ W_out (16384x1024x2048)
    gemm256<float><<<dim3(1024 / 256, NROWS / 256), 512, 0, stream>>>(xc, WoutT, out, NROWS, 1024, 2048);
}

// Round 6
// 428.122 us; speedup vs baseline: 1.0486x; 1.0486x over previous
//
#include <hip/hip_runtime.h>

// ---------------------------------------------------------------------------
// MambaLayer on MI355X (gfx950).
// Pipeline (all f16 MFMA with fp32 accumulate; scan/elementwise in fp32):
//   1. convert x -> f16; transpose-convert W_in, W_out -> N-major f16 (B^T form)
//   2. GEMM1: xr = x @ W_in          (16384x4096x1024)
//   3. conv_bc_fin: conv(3)+SiLU -> xc  AND  BtCt = xc @ [W_B|W_C] (MFMA)
//   4. scan_p2: carry propagation across chunks (tiny)
//   5. scan_p3_fuse: replay chunk scan -> ys, y-fuse -> overwrite xc (f16)
//   6. GEMM2: out = y @ W_out        (16384x1024x2048), fp32 out
//
// R6: gemm256 8-phase 256^2 BK=64 counted-vmcnt. 450us; GEMM1 157.7us.
// R7/R8: B-dedup half-pipeline. 437us; GEMM1 148.5us (MfmaUtil 39%).
// R9: 4Mx2N wave re-tile, af once/tile, B read one phase early. 153.7us,
//     MfmaUtil 39.1% — THIRD schedule variant at ~5600-5900 cyc/tile.
//     Conclusion: read placement is NOT the lever. Phase time matches
//     [CU ds_read drain 578] + [MFMA pipe 515] + overhead, phase-locked.
//     Remaining quantified cost: 4 sequential generations (1024 blocks,
//     1 block/CU) x (cold prologue + serialized C-write) on 16-tile K.
// R10: persistent multi-tile blocks. grid=256 exactly; block b -> col-panel
//     c=b%NC, row-group g=b/NC, RT row-tiles per block against the SAME
//     B col-panel (L2-hot restage at seams; b%8==c%8 aligns panel->XCD,
//     explicit swizzle dropped). Seam: [final barrier] -> stage next
//     prologue (5 halves) -> vmcnt(2) -> barrier -> frag preloads ->
//     C-write (stores drain under next tile's phases; placed AFTER the
//     gate so they don't inflate vmcnt). WAR at seams proved (buf0 last
//     read t=NT-2, buf1-Ah0 readers retired before final barrier).
//     MFMA loops s-outer (RAW distance 8). GEMM1: NC=16,RT=4; GEMM2: NC=4,RT=1.
// R11: verbatim resubmit of R10 — round-5 "container failed twice" matches
//     round-2's infra signature (resolved by resubmission); full audit
//     found no hang vector (uniform barriers, vmcnt ledger consistent,
//     seam WAR proven, no OOB, budgets unchanged from passing R9).
// ---------------------------------------------------------------------------

typedef _Float16 half8 __attribute__((ext_vector_type(8)));
typedef float floatx4 __attribute__((ext_vector_type(4)));

#define D_MODEL 1024
#define D_INNER 2048
#define SEQ     4096
#define NBATCH  4
#define NROWS   (NBATCH * SEQ)        // 16384
#define CHUNK   16
#define NCHUNK  (SEQ / CHUNK)         // 256 chunks per batch
#define NTASK   (NBATCH * NCHUNK)     // 1024 chunk-tasks

__device__ __forceinline__ void async16(_Float16* lds, const _Float16* g) {
    // global -> LDS direct copy, 16B per lane; LDS dest = wave-uniform base + lane*16
    __builtin_amdgcn_global_load_lds((const __attribute__((address_space(1))) void*)g,
                                     (__attribute__((address_space(3))) void*)lds, 16, 0, 0);
}

__device__ __forceinline__ float siluf(float x) {
    return x / (1.f + __expf(-x));
}

__device__ __forceinline__ float decay_of(const float* A, int s) {
    return __expf(-log1pf(__expf(A[s])));   // exp(-softplus(A[s]))
}

// --------------------------- conversion kernels ----------------------------

__global__ __launch_bounds__(256) void convert_f32_f16(const float* __restrict__ src,
                                                       _Float16* __restrict__ dst) {
    size_t idx = ((size_t)blockIdx.x * 256 + threadIdx.x) * 8;
    float4 a = *(const float4*)(src + idx);
    float4 b = *(const float4*)(src + idx + 4);
    half8 o = {(_Float16)a.x, (_Float16)a.y, (_Float16)a.z, (_Float16)a.w,
               (_Float16)b.x, (_Float16)b.y, (_Float16)b.z, (_Float16)b.w};
    *(half8*)(dst + idx) = o;
}

// src: K x N fp32 (row-major), dst: N x K f16 (row-major)  [i.e. B^T]
__global__ __launch_bounds__(256) void transpose_to_f16(const float* __restrict__ src,
                                                        _Float16* __restrict__ dst,
                                                        int K, int N) {
    __shared__ float tile[32][33];
    int n0 = blockIdx.x * 32, k0 = blockIdx.y * 32;
    int x = threadIdx.x, y = threadIdx.y;   // 32 x 8
#pragma unroll
    for (int r = 0; r < 32; r += 8)
        tile[y + r][x] = src[(size_t)(k0 + y + r) * N + (n0 + x)];
    __syncthreads();
#pragma unroll
    for (int r = 0; r < 32; r += 8)
        dst[(size_t)(n0 + y + r) * K + (k0 + x)] = (_Float16)tile[x][y + r];
}

// WBCT[n][k], n<16 -> W_B[:,n], n>=16 -> W_C[:,n-16]; shape 32 x 2048 f16
__global__ __launch_bounds__(256) void convert_wbct(const float* __restrict__ WB,
                                                    const float* __restrict__ WC,
                                                    _Float16* __restrict__ WBCT) {
    int idx = blockIdx.x * 256 + threadIdx.x;   // 0 .. 65535
    int n = idx >> 11, k = idx & 2047;
    float v = (n < 16) ? WB[k * 16 + n] : WC[k * 16 + (n - 16)];
    WBCT[idx] = (_Float16)v;
}

// ------------------------------- main GEMM ---------------------------------
// C(MxN) = A(MxK) * B(KxN), B given as BT (NxK row-major). f16 in, fp32 acc.
// 256x256 tile, BK=64, 512 threads = 8 waves as 4M x 2N; per-wave output
// 64x128 = 4x8 frags of 16x16. LDS 128 KiB: A/B double-buffered per K-tile,
// each 256x64 f16 in 2 halves of 128 rows. 16B-chunk XOR swizzle: chunk c of
// row r at c^(r&7) (staging permutes the GLOBAL source column; LDS dest
// stays linear because global_load_lds writes base+lane*16).
//
// Persistent blocks: grid = 256; block b -> col-panel c=b%NC (col0=c*256),
// row-group g=b/NC, processes RT row-tiles rowBase+rt*256 vs the same
// B panel. Seam (between row-tiles): final K-loop barrier -> stage next
// prologue (5 half-tiles; B from L2) -> vmcnt(2) -> barrier -> frag
// preloads -> C-write of finished tile (stores drain under next phases).
//
// Per K-tile t, phases p0..p3 = col-blocks cb0..cb3 (32 cols each):
//   af (8 reads) loaded once per tile at p3(t-1)/seam; B-operand for phase
//   p read at phase p-1 into alternating bfA/bfB. Stage ring: p0:
//   Ah1(t+1)+Bh0(t+1); p1: Bh1(t+1); p2: Ah0(t+2); p3: gate vmcnt(2).

__device__ __forceinline__ void stage_half(const _Float16* __restrict__ src, int K,
                                           int rowBase, int k0, _Float16* ldsHalf) {
    const int tid = threadIdx.x;
    const int sr = tid >> 3, wid = tid >> 6;
    const int lc = ((tid & 7) ^ (sr & 7)) << 3;     // swizzled source col (elements)
#pragma unroll
    for (int r = 0; r < 2; r++) {
        const _Float16* g = src + (size_t)(rowBase + r * 64 + sr) * K + (k0 + lc);
        async16(ldsHalf + r * 4096 + wid * 512, g);
    }
}

__device__ __forceinline__ void loadA8(half8 af[4][2], const _Float16* p,
                                       int sw0, int sw1) {
#pragma unroll
    for (int m = 0; m < 4; m++) {
        af[m][0] = *(const half8*)(p + m * 1024 + sw0);
        af[m][1] = *(const half8*)(p + m * 1024 + sw1);
    }
}

__device__ __forceinline__ void loadB4(half8 bf[2][2], const _Float16* p,
                                       int sw0, int sw1) {
#pragma unroll
    for (int n = 0; n < 2; n++) {
        bf[n][0] = *(const half8*)(p + n * 1024 + sw0);
        bf[n][1] = *(const half8*)(p + n * 1024 + sw1);
    }
}

// s-outer MFMA sweep: 8 independent MFMAs per k-slice (RAW distance 8)
#define GP_MMA(CB, BF)                                                                  \
    __builtin_amdgcn_s_barrier();                                                       \
    __builtin_amdgcn_s_setprio(1);                                                      \
    _Pragma("unroll") for (int s = 0; s < 2; s++)                                       \
        _Pragma("unroll") for (int m = 0; m < 4; m++)                                   \
            _Pragma("unroll") for (int n = 0; n < 2; n++)                               \
                acc[m][(CB) * 2 + n] = __builtin_amdgcn_mfma_f32_16x16x32_f16(          \
                    af[m][s], (BF)[n][s], acc[m][(CB) * 2 + n], 0, 0, 0);               \
    __builtin_amdgcn_s_setprio(0);                                                      \
    __builtin_amdgcn_s_barrier();

template <typename OutT, int NC, int RT>
__global__ __launch_bounds__(512, 2) void gemm256(const _Float16* __restrict__ A,
                                                  const _Float16* __restrict__ BT,
                                                  OutT* __restrict__ C,
                                                  int M, int N, int K) {
    __shared__ __align__(16) _Float16 smem[4 * 16384];   // 128 KiB: A0,A1,B0,B1
    _Float16* const AsBase = smem;
    _Float16* const BsBase = smem + 32768;

    const int tid = threadIdx.x;
    const int wid = tid >> 6, lane = tid & 63;
    const int wm = wid >> 1, wn = wid & 1;               // 4M x 2N waves
    const int fr = lane & 15, q = lane >> 4, frq = fr & 7;
    const int sw0 = (q ^ frq) << 3;                      // kk=0 swizzled chunk offset
    const int sw1 = ((4 + q) ^ frq) << 3;                // kk=1
    const int aB0 = (wm * 64 + fr) * 64;                 // af row base (+m*1024)
    const int bB0 = (wn * 128 + fr) * 64;                // bf base (+cb*2048 +n*1024)

    // persistent mapping: col-panel c = b%NC (b%8==c%8 -> panel pinned to XCD),
    // row-group g = b/NC owns RT consecutive row-tiles.
    const int b = blockIdx.x;
    const int col0 = (b % NC) * 256;
    const int rowBase = (b / NC) * (RT * 256);
    const int NT = K >> 6;

    half8 af[4][2], bfA[2][2], bfB[2][2];

    // Initial prologue: tile0 fully + tile1 A-h0.
    stage_half(A,  K, rowBase,       0, AsBase);         // t0 A-h0
    stage_half(A,  K, rowBase + 128, 0, AsBase + 8192);  // t0 A-h1
    stage_half(BT, K, col0,          0, BsBase);         // t0 B-h0
    stage_half(BT, K, col0 + 128,    0, BsBase + 8192);  // t0 B-h1
    stage_half(A,  K, rowBase,      64, AsBase + 16384); // t1 A-h0
    asm volatile("s_waitcnt vmcnt(2)" ::: "memory");
    __builtin_amdgcn_s_barrier();
    asm volatile("" ::: "memory");                       // no LDS-read hoist above barrier
    loadB4(bfA, BsBase + bB0, sw0, sw1);                 // t0 cb0
    loadA8(af, AsBase + aB0, sw0, sw1);                  // t0 A frags (all phases)

    for (int rt = 0; rt < RT; ++rt) {
        const int row0 = rowBase + rt * 256;
        floatx4 acc[4][8] = {};

        for (int t = 0; t < NT; ++t) {
            _Float16* Ab  = AsBase + ((t & 1) << 14);
            _Float16* Bb  = BsBase + ((t & 1) << 14);
            _Float16* Abn = AsBase + (((t + 1) & 1) << 14);
            _Float16* Bbn = BsBase + (((t + 1) & 1) << 14);
            const int k1 = (t + 1) << 6, k2 = (t + 2) << 6;
            const bool s1 = (t + 1) < NT, s2 = (t + 2) < NT;

            // p0: MFMA(cb0, bfA); read bfB<-cb1; stage Ah1(t+1), Bh0(t+1)
            loadB4(bfB, Bb + bB0 + 2048, sw0, sw1);
            if (s1) {
                stage_half(A,  K, row0 + 128, k1, Abn + 8192);
                stage_half(BT, K, col0,       k1, Bbn);
            }
            GP_MMA(0, bfA);

            // p1: MFMA(cb1, bfB); read bfA<-cb2; stage Bh1(t+1)
            loadB4(bfA, Bb + bB0 + 4096, sw0, sw1);
            if (s1) stage_half(BT, K, col0 + 128, k1, Bbn + 8192);
            GP_MMA(1, bfB);

            // p2: MFMA(cb2, bfA); read bfB<-cb3; stage Ah0(t+2)
            loadB4(bfB, Bb + bB0 + 6144, sw0, sw1);
            if (s2) stage_half(A, K, row0, k2, Ab);
            GP_MMA(2, bfA);

            // p3: gate; barrier(open); read bfA<-cb0(t+1); MFMA(cb3, bfB);
            //     read af(t+1); barrier(close)
            if (s2) {
                asm volatile("s_waitcnt vmcnt(2)" ::: "memory");
            } else if (s1) {
                asm volatile("s_waitcnt vmcnt(0)" ::: "memory");
            }
            __builtin_amdgcn_s_barrier();
            asm volatile("" ::: "memory");               // no hoist above gate+barrier
            if (s1) loadB4(bfA, Bbn + bB0, sw0, sw1);
            __builtin_amdgcn_s_setprio(1);
#pragma unroll
            for (int s = 0; s < 2; s++)
#pragma unroll
                for (int m = 0; m < 4; m++)
#pragma unroll
                    for (int n = 0; n < 2; n++)
                        acc[m][6 + n] = __builtin_amdgcn_mfma_f32_16x16x32_f16(
                            af[m][s], bfB[n][s], acc[m][6 + n], 0, 0, 0);
            __builtin_amdgcn_s_setprio(0);
            if (s1) loadA8(af, Abn + aB0, sw0, sw1);     // next tile A frags
            __builtin_amdgcn_s_barrier();
        }

        // Seam: stage next row-tile's prologue (B panel L2-hot), gate,
        // preload frags; THEN write C so stores drain under next tile.
        // WAR: buf0 slots last read at t=NT-2 (>=8 barriers ago); buf1-Ah0
        // readers retired before the K-loop's final barrier (all waves).
        if (rt + 1 < RT) {
            const int row0n = row0 + 256;
            stage_half(A,  K, row0n,       0, AsBase);
            stage_half(A,  K, row0n + 128, 0, AsBase + 8192);
            stage_half(BT, K, col0,        0, BsBase);
            stage_half(BT, K, col0 + 128,  0, BsBase + 8192);
            stage_half(A,  K, row0n,      64, AsBase + 16384);
            asm volatile("s_waitcnt vmcnt(2)" ::: "memory");
            __builtin_amdgcn_s_barrier();
            asm volatile("" ::: "memory");
            loadB4(bfA, BsBase + bB0, sw0, sw1);
            loadA8(af, AsBase + aB0, sw0, sw1);
        }

        // C/D layout: col = lane&15, row = (lane>>4)*4 + reg   [measured m89/m91]
        const int er = (lane >> 4) * 4, ec = lane & 15;
#pragma unroll
        for (int mi = 0; mi < 4; mi++)
#pragma unroll
            for (int cj = 0; cj < 8; cj++)
#pragma unroll
                for (int r = 0; r < 4; r++) {
                    int row = row0 + wm * 64 + mi * 16 + er + r;
                    int col = col0 + wn * 128 + cj * 16 + ec;
                    C[(size_t)row * N + col] = (OutT)acc[mi][cj][r];
                }
    }
}

// ---------------- fused conv + silu + Bt/Ct (MFMA) + scan p1 ----------------
// Block = 32 rows (2 chunks), 256 threads = 4 waves. Waves own disjoint K
// quarters (512 cols = 4 panels of 128) -> NO barriers in the main loop.
__global__ __launch_bounds__(256) void conv_bc_fin(const _Float16* __restrict__ xr,
                                                   const float* __restrict__ cw,
                                                   const float* __restrict__ cb,
                                                   const _Float16* __restrict__ WBCT,
                                                   const float* __restrict__ A,
                                                   _Float16* __restrict__ xc,
                                                   float* __restrict__ BtCt,
                                                   float* __restrict__ fin) {
    __shared__ __align__(16) _Float16 As[4 * 32 * 128];   // 32 KB; reused in epilogue
    const int tid = threadIdx.x, wid = tid >> 6, lane = tid & 63;
    const int row0 = blockIdx.x * 32;
    const int l0 = row0 & (SEQ - 1);
    const int cg = lane & 15;            // col-group within panel (8 cols)
    const int rg = lane >> 4;            // row-group (8 rows)
    const int fr = lane & 15, q = lane >> 4;
    _Float16* As_w = As + wid * 4096;
    const int r0 = rg * 8;

    floatx4 acc[2][2] = {};

    for (int t = 0; t < 4; t++) {
        const int kbase = wid * 512 + t * 128;
        const int gcol = kbase + cg * 8;
        float w0[8], w1[8], w2[8], bb[8];
#pragma unroll
        for (int j = 0; j < 8; j++) {
            w0[j] = cw[(gcol + j) * 3];
            w1[j] = cw[(gcol + j) * 3 + 1];
            w2[j] = cw[(gcol + j) * 3 + 2];
            bb[j] = cb[gcol + j];
        }
        half8 prev = {}, cur, nxt;
        if (!(l0 == 0 && rg == 0))
            prev = *(const half8*)(xr + (size_t)(row0 + r0 - 1) * 4096 + gcol);
        cur = *(const half8*)(xr + (size_t)(row0 + r0) * 4096 + gcol);
#pragma unroll
        for (int r = 0; r < 8; r++) {
            if (r == 7 && rg == 3 && l0 + 32 == SEQ) {
                half8 z = {};
                nxt = z;
            } else {
                nxt = *(const half8*)(xr + (size_t)(row0 + r0 + r + 1) * 4096 + gcol);
            }
            half8 o;
#pragma unroll
            for (int j = 0; j < 8; j++) {
                float a = (float)prev[j] * w0[j] + (float)cur[j] * w1[j] +
                          (float)nxt[j] * w2[j] + bb[j];
                o[j] = (_Float16)siluf(a);
            }
            const int lrow = r0 + r;
            *(half8*)(xc + (size_t)(row0 + lrow) * D_INNER + gcol) = o;
            *(half8*)(As_w + lrow * 128 + ((cg ^ (lrow & 7)) * 8)) = o;
            prev = cur;
            cur = nxt;
        }
#pragma unroll
        for (int ks = 0; ks < 4; ks++) {
            half8 af[2], bf[2];
#pragma unroll
            for (int rt = 0; rt < 2; rt++)
                af[rt] = *(const half8*)(As_w + (rt * 16 + fr) * 128 +
                                         (((ks * 4 + q) ^ (fr & 7)) * 8));
#pragma unroll
            for (int ot = 0; ot < 2; ot++)
                bf[ot] = *(const half8*)(WBCT + (size_t)(ot * 16 + fr) * D_INNER +
                                         kbase + ks * 32 + q * 8);
#pragma unroll
            for (int rt = 0; rt < 2; rt++)
#pragma unroll
                for (int ot = 0; ot < 2; ot++)
                    acc[rt][ot] = __builtin_amdgcn_mfma_f32_16x16x32_f16(af[rt], bf[ot], acc[rt][ot], 0, 0, 0);
        }
    }

    __syncthreads();                       // all waves done reading As as f16
    float* red = (float*)As;               // [wid][row 32][out 32] = 4096 f32 (16 KB)
    float* btl = (float*)As + 4096;        // [row 32][out 32] = 1024 f32 (4 KB)
    const int er = (lane >> 4) * 4, ec = lane & 15;
#pragma unroll
    for (int rt = 0; rt < 2; rt++)
#pragma unroll
        for (int ot = 0; ot < 2; ot++)
#pragma unroll
            for (int rr = 0; rr < 4; rr++)
                red[wid * 1024 + (rt * 16 + er + rr) * 32 + ot * 16 + ec] = acc[rt][ot][rr];
    __syncthreads();
#pragma unroll
    for (int i = 0; i < 4; i++) {
        int idx = i * 256 + tid;           // (row<<5)|out
        float v = red[idx] + red[1024 + idx] + red[2048 + idx] + red[3072 + idx];
        btl[idx] = v;
        BtCt[(size_t)row0 * 32 + idx] = v; // (row0+row)*32+out == row0*32+idx
    }
    __syncthreads();
    if (tid < 32) {                        // 2 chunks x 16 states
        const int ch = tid >> 4, s = tid & 15;
        const float decay = decay_of(A, s);
        float st = 0.f;
#pragma unroll
        for (int r = 0; r < CHUNK; r++)
            st = st * decay + btl[(ch * 16 + r) * 32 + s];
        fin[((row0 >> 4) + ch) * 16 + s] = st;
    }
}

// -------------------------------- scan -------------------------------------
// phase 2: carry propagation across chunks. 1 block x 64 threads (b,s).
__global__ __launch_bounds__(64) void scan_p2(const float* __restrict__ fin,
                                              const float* __restrict__ A,
                                              float* __restrict__ carry) {
    int t = threadIdx.x;
    int b = t >> 4, s = t & 15;
    float decay = decay_of(A, s);
    float d16 = decay;
#pragma unroll
    for (int k = 0; k < 4; k++) d16 *= d16;     // decay^16
    float cy = 0.f;
#pragma unroll 8
    for (int c = 0; c < NCHUNK; c++) {
        int idx = ((b * NCHUNK) + c) * 16 + s;
        carry[idx] = cy;
        cy = cy * d16 + fin[idx];
    }
}

// phase 3 + y-fuse: replay chunk scan (lanes 0..15, Bt/Ct preloaded to regs)
// -> ys in LDS, then all 256 threads compute y = (ys + xc*D) * silu(res),
// overwriting xc (f16). 1024 blocks x 256 threads; block = chunk-task.
__global__ __launch_bounds__(256) void scan_p3_fuse(const float* __restrict__ BtCt,
                                                    const float* __restrict__ A,
                                                    const float* __restrict__ carry,
                                                    const float* __restrict__ D,
                                                    const _Float16* __restrict__ xr,
                                                    _Float16* __restrict__ xc) {
    __shared__ float ysl[CHUNK];
    const int task = blockIdx.x;
    const int b = task >> 8, c = task & (NCHUNK - 1);
    const int row0 = b * SEQ + c * CHUNK;
    const int tid = threadIdx.x;

    if (tid < 16) {
        const int s = tid;
        const float decay = decay_of(A, s);
        size_t r = (size_t)row0 * 32;
        float bt[CHUNK], ct[CHUNK];
#pragma unroll
        for (int j = 0; j < CHUNK; j++) {       // independent loads, ILP
            bt[j] = BtCt[r + (size_t)j * 32 + s];
            ct[j] = BtCt[r + (size_t)j * 32 + 16 + s];
        }
        float st = carry[task * 16 + s];
        float yv[CHUNK];
#pragma unroll
        for (int j = 0; j < CHUNK; j++) {       // serial FMA chain only
            st = st * decay + bt[j];
            yv[j] = st * ct[j];
        }
#pragma unroll
        for (int j = 0; j < CHUNK; j++) {       // 16 independent reduce chains
            float y = yv[j];
            y += __shfl_xor(y, 1, 16);
            y += __shfl_xor(y, 2, 16);
            y += __shfl_xor(y, 4, 16);
            y += __shfl_xor(y, 8, 16);
            if (s == 0) ysl[j] = y;
        }
    }
    __syncthreads();

#pragma unroll
    for (int it = 0; it < 16; it++) {
        int chunk = it * 256 + tid;            // 0..4095 (16 rows x 256 col-chunks)
        int rl = chunk >> 8;                   // row within chunk
        int colb = (chunk & 255) * 8;          // col offset (elements)
        size_t row = (size_t)(row0 + rl);
        float yv = ysl[rl];
        half8 x8 = *(const half8*)(xc + row * D_INNER + colb);
        half8 r8 = *(const half8*)(xr + row * 4096 + 2048 + colb);
        float4 d0 = *(const float4*)(D + colb);
        float4 d1 = *(const float4*)(D + colb + 4);
        half8 o;
        float dd[8] = {d0.x, d0.y, d0.z, d0.w, d1.x, d1.y, d1.z, d1.w};
#pragma unroll
        for (int j = 0; j < 8; j++) {
            float y = yv + (float)x8[j] * dd[j];
            o[j] = (_Float16)(y * siluf((float)r8[j]));
        }
        *(half8*)(xc + row * D_INNER + colb) = o;
    }
}

// ------------------------------- launcher ----------------------------------
extern "C" void kernel_launch(void* const* d_in, const int* in_sizes, int n_in,
                              void* d_out, int out_size, void* d_ws, size_t ws_size,
                              hipStream_t stream) {
    const float* x      = (const float*)d_in[0];
    const float* W_in   = (const float*)d_in[1];
    const float* conv_w = (const float*)d_in[2];
    const float* conv_b = (const float*)d_in[3];
    const float* W_B    = (const float*)d_in[4];
    const float* W_C    = (const float*)d_in[5];
    const float* A      = (const float*)d_in[6];
    const float* D      = (const float*)d_in[7];
    const float* W_out  = (const float*)d_in[8];
    float* out = (float*)d_out;

    char* ws = (char*)d_ws;
    size_t off = 0;
    auto alloc = [&](size_t bytes) { size_t o = off; off += (bytes + 255) & ~(size_t)255; return o; };
    _Float16* xh    = (_Float16*)(ws + alloc((size_t)NROWS * D_MODEL * 2));      // 33.5 MB
    _Float16* WinT  = (_Float16*)(ws + alloc((size_t)4096 * 1024 * 2));          //  8.4 MB
    _Float16* WoutT = (_Float16*)(ws + alloc((size_t)1024 * 2048 * 2));          //  4.2 MB
    _Float16* WBCT  = (_Float16*)(ws + alloc((size_t)32 * 2048 * 2));            //  0.13 MB
    _Float16* xr    = (_Float16*)(ws + alloc((size_t)NROWS * 4096 * 2));         //  134 MB
    _Float16* xc    = (_Float16*)(ws + alloc((size_t)NROWS * D_INNER * 2));      //   67 MB
    float*    BtCt  = (float*)(ws + alloc((size_t)NROWS * 32 * 4));              //    2 MB
    float*    fin   = (float*)(ws + alloc((size_t)NTASK * 16 * 4));              //  64 KB
    float*    carry = (float*)(ws + alloc((size_t)NTASK * 16 * 4));              //  64 KB

    // 1. conversions
    convert_f32_f16<<<(NROWS * D_MODEL) / (256 * 8), 256, 0, stream>>>(x, xh);
    transpose_to_f16<<<dim3(4096 / 32, 1024 / 32), dim3(32, 8), 0, stream>>>(W_in, WinT, 1024, 4096);
    transpose_to_f16<<<dim3(1024 / 32, 2048 / 32), dim3(32, 8), 0, stream>>>(W_out, WoutT, 2048, 1024);
    convert_wbct<<<(32 * 2048) / 256, 256, 0, stream>>>(W_B, W_C, WBCT);
    // 2. GEMM1: xr = x @ W_in   (16384x4096x1024); 256 persistent blocks,
    //    16 col-panels x 16 row-groups x 4 row-tiles
    gemm256<_Float16, 16, 4><<<256, 512, 0, stream>>>(xh, WinT, xr, NROWS, 4096, 1024);
    // 3. conv + silu + Bt/Ct + fin (fused, MFMA)
    conv_bc_fin<<<NROWS / 32, 256, 0, stream>>>(xr, conv_w, conv_b, WBCT, A, xc, BtCt, fin);
    // 4. scan phase 2
    scan_p2<<<1, 64, 0, stream>>>(fin, A, carry);
    // 5. scan phase 3 + y-fuse
    scan_p3_fuse<<<NTASK, 256, 0, stream>>>(BtCt, A, carry, D, xr, xc);
    // 6. GEMM2: out = y @ W_out (16384x1024x2048); 4 col-panels x 64 row-groups
    gemm256<float, 4, 1><<<256, 512, 0, stream>>>(xc, WoutT, out, NROWS, 1024, 2048);
}